// Round 15
// baseline (119.692 us; speedup 1.0000x reference)
//
#include <hip/hip_runtime.h>
#include <math.h>

namespace {

constexpr int Nn = 8192;   // N
constexpr int Ss = 1024;   // S
constexpr float F_EPS = 1e-7f;
constexpr float F_BN_EPS = 1e-5f;

typedef __attribute__((ext_vector_type(8))) short s16x8;   // 8 bf16 = 4 VGPR
typedef __attribute__((ext_vector_type(4))) float f32x4;   // MFMA acc

// ---- d_ws layout (bytes) ----
constexpr int WB3 = 0;            // bf16 [128][128] conv3 weights, BN-folded (linear k)
constexpr int WB4 = 32768;        // bf16 [256][128] conv4 weights, BN-folded (linear k; fallback)
constexpr int BB3 = 98304;        // f32 [128]
constexpr int BB4 = 98816;        // f32 [256]
constexpr int EW1 = 99840;        // f32 [32][8]
constexpr int EB1 = 100864;       // f32 [32]
constexpr int EW2 = 100992;       // f32 [64][32]
constexpr int EB2 = 109184;       // f32 [64]
constexpr size_t WS_NEED = 109440;

// big-workspace path
constexpr size_t CATO = 131072;                       // cat[262144][64] bf16 = 32MB
constexpr size_t PVT  = CATO + 33554432ull;           // prevT[8][8192][64] bf16 = 8MB
constexpr size_t WB4P = PVT + 8388608ull;             // bf16 [256][128] conv4 weights, k sigma-permuted
constexpr size_t WS_BIG = WB4P + 65536ull;

__device__ inline unsigned short f2bf(float f) {  // RNE f32 -> bf16
  unsigned int u = __builtin_bit_cast(unsigned int, f);
  u += 0x7fffu + ((u >> 16) & 1u);
  return (unsigned short)(u >> 16);
}

__device__ inline s16x8 pack_scaled(const float* __restrict__ p, float sc) {
  const float4 w0 = *(const float4*)p;
  const float4 w1 = *(const float4*)(p + 4);
  s16x8 r;
  r[0] = (short)f2bf(w0.x * sc); r[1] = (short)f2bf(w0.y * sc);
  r[2] = (short)f2bf(w0.z * sc); r[3] = (short)f2bf(w0.w * sc);
  r[4] = (short)f2bf(w1.x * sc); r[5] = (short)f2bf(w1.y * sc);
  r[6] = (short)f2bf(w1.z * sc); r[7] = (short)f2bf(w1.w * sc);
  return r;
}

// A-fragment from prev[b][c][n] (fallback path only; validated R1)
__device__ inline s16x8 prev_frag(const float* __restrict__ prev, int b, int cbase, int n) {
  const float* p = prev + (size_t)(b * 64 + cbase) * Nn + n;
  s16x8 r;
#pragma unroll
  for (int j = 0; j < 8; ++j) r[j] = (short)f2bf(p[j * Nn]);
  return r;
}

__device__ inline int ci_of(int s) {
  return (s == Ss - 1) ? (Nn - 1) : (int)(long long)((double)s * (8191.0 / 1023.0));
}

// features for one row: exact arithmetic/order of the validated k1f2 body
__device__ inline void feat8(const float2* __restrict__ c2, const float2* __restrict__ l2,
                             int b, int s, int kk, float* __restrict__ rif)
{
  const int ci = ci_of(s);
  const int n = (ci - 16 + kk) & (Nn - 1);

  const float2 xi = c2[b * Nn + n];
  const float2 lx = l2[b * Nn + n];
  const float2 sp = c2[b * Nn + ci];
  const float2 lc = l2[b * Nn + ci];

  float2 xim1 = make_float2(0.f, 0.f), lxm1 = make_float2(0.f, 0.f);
  if (kk > 0) {
    const int np = (ci - 16 + kk - 1) & (Nn - 1);
    xim1 = c2[b * Nn + np];
    lxm1 = l2[b * Nn + np];
  }

  const float vx = xi.x - sp.x, vy = xi.y - sp.y;
  const float f4 = sqrtf(vx * vx + vy * vy);
  const float inv = 1.0f / (f4 + F_EPS);
  const float ux = vx * inv, uy = vy * inv;
  const float a1 = lc.x * ux + lc.y * uy;
  const float a2 = -(lx.x * ux + lx.y * uy);
  float dotp = lx.x * lc.x + lx.y * lc.y;
  float cl = fminf(fmaxf(dotp, -1.0f + F_EPS), 1.0f - F_EPS);
  const float f3o = (a1 < a2 ? 1.0f : -1.0f) * acosf(cl);

  float pux = 0.f, puy = 0.f;
  if (kk > 0) {
    const float pvx = xim1.x - sp.x, pvy = xim1.y - sp.y;
    const float pf4 = sqrtf(pvx * pvx + pvy * pvy);
    const float pinv = 1.0f / (pf4 + F_EPS);
    pux = pvx * pinv; puy = pvy * pinv;
  }
  const float vpx = (kk > 0) ? (xi.x - xim1.x) : 0.0f;
  const float vpy = (kk > 0) ? (xi.y - xim1.y) : 0.0f;
  const float f8 = sqrtf(vpx * vpx + vpy * vpy);
  const float invp = 1.0f / (f8 + F_EPS);
  const float upx = vpx * invp, upy = vpy * invp;
  const float a4 = upx * lx.x + upy * lx.y;
  const float a5 = upx * lxm1.x + upy * lxm1.y;
  float dotp2 = lx.x * lxm1.x + lx.y * lxm1.y;
  float cl2 = fminf(fmaxf(dotp2, -1.0f + F_EPS), 1.0f - F_EPS);
  const float f7o = (a4 < a5 ? 1.0f : -1.0f) * acosf(cl2);
  float du = ux * pux + uy * puy;
  float cl3 = fminf(fmaxf(du, -1.0f + F_EPS), 1.0f - F_EPS);
  const float d2 = acosf(cl3);

  rif[0] = f4;  rif[1] = d2;  rif[2] = a1; rif[3] = a2;
  rif[4] = f3o; rif[5] = a4;  rif[6] = a5; rif[7] = f7o;
}

// ---------- prep: fold BN into weights/biases, bf16-convert GEMM weights ----------
__global__ __launch_bounds__(256) void rcri_prep(
    const float* __restrict__ ew1, const float* __restrict__ eb1,
    const float* __restrict__ eg1, const float* __restrict__ ebeta1,
    const float* __restrict__ em1, const float* __restrict__ ev1,
    const float* __restrict__ ew2, const float* __restrict__ eb2,
    const float* __restrict__ eg2, const float* __restrict__ ebeta2,
    const float* __restrict__ em2, const float* __restrict__ ev2,
    const float* __restrict__ fw1, const float* __restrict__ fb1,
    const float* __restrict__ fg1, const float* __restrict__ fbeta1,
    const float* __restrict__ fm1, const float* __restrict__ fv1,
    const float* __restrict__ fw2, const float* __restrict__ fb2,
    const float* __restrict__ fg2, const float* __restrict__ fbeta2,
    const float* __restrict__ fm2, const float* __restrict__ fv2,
    unsigned char* __restrict__ ws)
{
  const int i = blockIdx.x * 256 + threadIdx.x;
  if (i < 16384) {
    const int o = i >> 7;
    const float sc = fg1[o] * rsqrtf(fv1[o] + F_BN_EPS);
    ((unsigned short*)(ws + WB3))[i] = f2bf(fw1[i] * sc);
    return;
  }
  int j = i - 16384;
  if (j < 32768) {
    const int o = j >> 7;
    const float sc = fg2[o] * rsqrtf(fv2[o] + F_BN_EPS);
    ((unsigned short*)(ws + WB4))[j] = f2bf(fw2[j] * sc);
    return;
  }
  j -= 32768;
  if (j < 128) {
    const float sc = fg1[j] * rsqrtf(fv1[j] + F_BN_EPS);
    ((float*)(ws + BB3))[j] = (fb1[j] - fm1[j]) * sc + fbeta1[j];
    return;
  }
  j -= 128;
  if (j < 256) {
    const float sc = fg2[j] * rsqrtf(fv2[j] + F_BN_EPS);
    ((float*)(ws + BB4))[j] = (fb2[j] - fm2[j]) * sc + fbeta2[j];
    return;
  }
  j -= 256;
  if (j < 256) {
    const int o = j >> 3;
    const float sc = eg1[o] * rsqrtf(ev1[o] + F_BN_EPS);
    ((float*)(ws + EW1))[j] = ew1[j] * sc;
    return;
  }
  j -= 256;
  if (j < 32) {
    const float sc = eg1[j] * rsqrtf(ev1[j] + F_BN_EPS);
    ((float*)(ws + EB1))[j] = (eb1[j] - em1[j]) * sc + ebeta1[j];
    return;
  }
  j -= 32;
  if (j < 2048) {
    const int o = j >> 5;
    const float sc = eg2[o] * rsqrtf(ev2[o] + F_BN_EPS);
    ((float*)(ws + EW2))[j] = ew2[j] * sc;
    return;
  }
  j -= 2048;
  if (j < 64) {
    const float sc = eg2[j] * rsqrtf(ev2[j] + F_BN_EPS);
    ((float*)(ws + EB2))[j] = (eb2[j] - em2[j]) * sc + ebeta2[j];
  }
}

// ---------- prep2 (big path only): sigma-permuted conv4 weights ----------
__global__ __launch_bounds__(256) void rcri_prep2(
    const float* __restrict__ fw2, const float* __restrict__ fg2,
    const float* __restrict__ fv2, unsigned char* __restrict__ ws)
{
  const int j = blockIdx.x * 256 + threadIdx.x;   // 0..32767
  const int o = j >> 7;
  const int jk = j & 127;
  const int c = 32 * (jk >> 5) + 16 * (jk & 1) + ((jk & 31) >> 1);
  const float sc = fg2[o] * rsqrtf(fv2[o] + F_BN_EPS);
  ((unsigned short*)(ws + WB4P))[j] = f2bf(fw2[o * 128 + c] * sc);
}

// ---------- tpose: prev[b][c][n] f32 -> prevT[b][n][64] bf16 ----------
__global__ __launch_bounds__(256) void rcri_tpose(
    const float* __restrict__ prev, unsigned char* __restrict__ ws)
{
  __shared__ unsigned short tile[128 * 72];
  const int t = threadIdx.x;
  const int b = blockIdx.x >> 6;
  const int n0 = (blockIdx.x & 63) * 128;
  const int nloc = t & 127;
  const int chalf = t >> 7;

#pragma unroll
  for (int it = 0; it < 32; ++it) {
    const int c = it * 2 + chalf;
    const float v = prev[(size_t)(b * 64 + c) * Nn + n0 + nloc];
    tile[nloc * 72 + c] = f2bf(v);
  }
  __syncthreads();

#pragma unroll
  for (int it = 0; it < 4; ++it) {
    const int idx = it * 256 + t;
    const int rn = idx >> 3;
    const int cc = idx & 7;
    const uint4 v = *(const uint4*)((const unsigned char*)tile + rn * 144 + cc * 16);
    *(uint4*)(ws + PVT + (size_t)(b * Nn + n0 + rn) * 128 + cc * 16) = v;
  }
}

// ---------- K1p: features + conv1 + conv2 (f32, LDS weights, ROW-PAIR amortized) ----------
// Each thread handles rows r0 and r0+128 of its block's 256 rows; every weight register
// load is reused across both rows (halves LDS broadcast traffic per row). Math identical
// to validated k1f2 (same operand order per dot product).
__global__ __launch_bounds__(256) void rcri_k1p(
    const float* __restrict__ contour, const float* __restrict__ loa,
    unsigned char* __restrict__ ws)
{
  __shared__ float wlds[2400];   // ew1'[32][8] | eb1'[32] | ew2'[64][32] | eb2'[64]
  __shared__ __align__(16) unsigned char cstage[256 * 144];  // [row][64ch bf16], 144B pitch

  const int t = threadIdx.x;
  for (int j = t; j < 2400; j += 256) wlds[j] = ((const float*)(ws + EW1))[j];

  const int r0 = t & 127;
  const int hf = t >> 7;
  const int rows0 = blockIdx.x * 256;

  const float2* c2 = (const float2*)contour;
  const float2* l2 = (const float2*)loa;

  float rifA[8], rifB[8];
  {
    const int rowA = rows0 + r0;
    feat8(c2, l2, rowA >> 15, (rowA >> 5) & 1023, rowA & 31, rifA);
    const int rowB = rowA + 128;
    feat8(c2, l2, rowB >> 15, (rowB >> 5) & 1023, rowB & 31, rifB);
  }

  __syncthreads();  // wlds ready

  // conv1: 8 -> 32 for both rows; weights read once per output
  float h1A[32], h1B[32];
#pragma unroll
  for (int o = 0; o < 32; ++o) {
    const float4 w0 = *(const float4*)(wlds + o * 8);
    const float4 w1 = *(const float4*)(wlds + o * 8 + 4);
    const float bb = wlds[256 + o];
    const float accA = bb
      + w0.x * rifA[0] + w0.y * rifA[1] + w0.z * rifA[2] + w0.w * rifA[3]
      + w1.x * rifA[4] + w1.y * rifA[5] + w1.z * rifA[6] + w1.w * rifA[7];
    const float accB = bb
      + w0.x * rifB[0] + w0.y * rifB[1] + w0.z * rifB[2] + w0.w * rifB[3]
      + w1.x * rifB[4] + w1.y * rifB[5] + w1.z * rifB[6] + w1.w * rifB[7];
    h1A[o] = fmaxf(accA, 0.f);
    h1B[o] = fmaxf(accB, 0.f);
  }

  // conv2: this thread's 32 of 64 outputs for both rows; weights read once per output
#pragma unroll
  for (int grp = 0; grp < 4; ++grp) {
    unsigned int uuA[4], uuB[4];
#pragma unroll
    for (int q = 0; q < 4; ++q) {
      float yA[2], yB[2];
#pragma unroll
      for (int jj = 0; jj < 2; ++jj) {
        const int o = hf * 32 + grp * 8 + q * 2 + jj;
        float aA = wlds[2336 + o];
        float aB = aA;
#pragma unroll
        for (int c4 = 0; c4 < 8; ++c4) {
          const float4 ww = *(const float4*)(wlds + 288 + o * 32 + c4 * 4);
          aA += ww.x * h1A[c4 * 4 + 0] + ww.y * h1A[c4 * 4 + 1]
              + ww.z * h1A[c4 * 4 + 2] + ww.w * h1A[c4 * 4 + 3];
          aB += ww.x * h1B[c4 * 4 + 0] + ww.y * h1B[c4 * 4 + 1]
              + ww.z * h1B[c4 * 4 + 2] + ww.w * h1B[c4 * 4 + 3];
        }
        yA[jj] = fmaxf(aA, 0.f);
        yB[jj] = fmaxf(aB, 0.f);
      }
      uuA[q] = (unsigned)f2bf(yA[0]) | ((unsigned)f2bf(yA[1]) << 16);
      uuB[q] = (unsigned)f2bf(yB[0]) | ((unsigned)f2bf(yB[1]) << 16);
    }
    *(uint4*)(cstage + r0 * 144 + hf * 64 + grp * 16) = make_uint4(uuA[0], uuA[1], uuA[2], uuA[3]);
    *(uint4*)(cstage + (r0 + 128) * 144 + hf * 64 + grp * 16) = make_uint4(uuB[0], uuB[1], uuB[2], uuB[3]);
  }
  __syncthreads();

  // coalesced write-out: 256 rows x 128B
#pragma unroll
  for (int it = 0; it < 8; ++it) {
    const int idx = it * 256 + t;
    const int rr = idx >> 3;
    const int cc = idx & 7;
    const uint4 v = *(const uint4*)(cstage + rr * 144 + cc * 16);
    *(uint4*)(ws + CATO + (size_t)(blockIdx.x * 256 + rr) * 128 + cc * 16) = v;
  }
}

// ---------- K23: bulk-staged conv3 (h3 aliased onto stage) + conv4 + max (R12 verbatim) ----------
__global__ __launch_bounds__(256) void rcri_k23(
    const unsigned char* __restrict__ ws, float* __restrict__ out)
{
  __shared__ __align__(16) unsigned char stage[32768];
  __shared__ float obuf[256 * 5];

  const int t = threadIdx.x;
  const int lane = t & 63;
  const int w = t >> 6;
  const int rl = lane & 15;
  const int g = lane >> 4;
  const int rows0 = blockIdx.x * 128;   // 4 samples
  const int b = blockIdx.x >> 8;
  const int sbase = (blockIdx.x & 255) * 4;

  const unsigned char* catp = ws + CATO + (size_t)rows0 * 128;
  const unsigned char* pvtp = ws + PVT + (size_t)b * Nn * 128;

  // ---- bulk stage: 8 loads in flight per thread, then LDS writes ----
  {
    const int slot = t & 15;
    uint4 v[8];
#pragma unroll
    for (int i = 0; i < 8; ++i) {
      const int row = i * 16 + (t >> 4);
      const int c = slot ^ (row & 15);
      const unsigned char* src;
      if (c < 8) {
        src = catp + (size_t)row * 128 + c * 16;
      } else {
        const int rg = rows0 + row;
        const int s = (rg >> 5) & 1023;
        const int kk = rg & 31;
        const int n = (ci_of(s) - 16 + kk) & (Nn - 1);
        src = pvtp + (size_t)n * 128 + (c - 8) * 16;
      }
      v[i] = *(const uint4*)src;
    }
#pragma unroll
    for (int i = 0; i < 8; ++i)
      *(uint4*)(stage + i * 4096 + t * 16) = v[i];
  }
  __syncthreads();

  // ---- conv3: 128 -> 128 from staged LDS; h3 written IN PLACE over stage rows ----
  {
    const unsigned short* wb3 = (const unsigned short*)(ws + WB3);
    const float* b3p = (const float*)(ws + BB3);
    s16x8 B3[2][4];
    float bb3[2];
#pragma unroll
    for (int i = 0; i < 2; ++i) {
      const int o = (2 * w + i) * 16 + rl;
#pragma unroll
      for (int kt = 0; kt < 4; ++kt)
        B3[i][kt] = *(const s16x8*)(wb3 + o * 128 + kt * 32 + 8 * g);
      bb3[i] = b3p[o];
    }
    for (int mt = 0; mt < 8; ++mt) {
      const int rowl = mt * 16 + rl;
      const int sw = (rowl & 15) << 4;
      const s16x8 a0 = __builtin_bit_cast(s16x8, *(const uint4*)(stage + rowl * 256 + ((16 * (g))      ^ sw)));
      const s16x8 a1 = __builtin_bit_cast(s16x8, *(const uint4*)(stage + rowl * 256 + ((16 * (4 + g))  ^ sw)));
      const s16x8 a2 = __builtin_bit_cast(s16x8, *(const uint4*)(stage + rowl * 256 + ((16 * (8 + g))  ^ sw)));
      const s16x8 a3 = __builtin_bit_cast(s16x8, *(const uint4*)(stage + rowl * 256 + ((16 * (12 + g)) ^ sw)));

      __syncthreads();  // all waves' reads of this mt's rows complete before in-place writes

      f32x4 acc0 = {bb3[0], bb3[0], bb3[0], bb3[0]};
      f32x4 acc1 = {bb3[1], bb3[1], bb3[1], bb3[1]};
      acc0 = __builtin_amdgcn_mfma_f32_16x16x32_bf16(a0, B3[0][0], acc0, 0, 0, 0);
      acc0 = __builtin_amdgcn_mfma_f32_16x16x32_bf16(a1, B3[0][1], acc0, 0, 0, 0);
      acc0 = __builtin_amdgcn_mfma_f32_16x16x32_bf16(a2, B3[0][2], acc0, 0, 0, 0);
      acc0 = __builtin_amdgcn_mfma_f32_16x16x32_bf16(a3, B3[0][3], acc0, 0, 0, 0);
      acc1 = __builtin_amdgcn_mfma_f32_16x16x32_bf16(a0, B3[1][0], acc1, 0, 0, 0);
      acc1 = __builtin_amdgcn_mfma_f32_16x16x32_bf16(a1, B3[1][1], acc1, 0, 0, 0);
      acc1 = __builtin_amdgcn_mfma_f32_16x16x32_bf16(a2, B3[1][2], acc1, 0, 0, 0);
      acc1 = __builtin_amdgcn_mfma_f32_16x16x32_bf16(a3, B3[1][3], acc1, 0, 0, 0);

#pragma unroll
      for (int r = 0; r < 4; ++r) {
        const int row2 = mt * 16 + 4 * g + r;
        const unsigned u = (unsigned)f2bf(fmaxf(acc0[r], 0.f))
                         | ((unsigned)f2bf(fmaxf(acc1[r], 0.f)) << 16);
        *(unsigned int*)(stage + row2 * 256 + ((64 * w + 4 * rl) ^ ((row2 & 15) << 4))) = u;
      }
    }
  }
  __syncthreads();

  // ---- conv4: 128 -> 256 (sigma-permuted weights) + relu-folded max over k ----
  {
    const unsigned short* wb4p = (const unsigned short*)(ws + WB4P);
    const float* b4p = (const float*)(ws + BB4);
    s16x8 B4[4][4];
    float bb4[4];
#pragma unroll
    for (int ni = 0; ni < 4; ++ni) {
      const int o = (4 * w + ni) * 16 + rl;
#pragma unroll
      for (int kt = 0; kt < 4; ++kt)
        B4[ni][kt] = *(const s16x8*)(wb4p + o * 128 + kt * 32 + 8 * g);
      bb4[ni] = b4p[o];
    }
    float vmax[4] = {0.f, 0.f, 0.f, 0.f};   // relu folded: max(0, max_k y)
#pragma unroll 2
    for (int mt = 0; mt < 8; ++mt) {
      const int rowl = mt * 16 + rl;
      s16x8 a[4];
#pragma unroll
      for (int kt = 0; kt < 4; ++kt)
        a[kt] = __builtin_bit_cast(s16x8,
            *(const uint4*)(stage + rowl * 256 + ((kt * 64 + 16 * g) ^ ((rowl & 15) << 4))));
#pragma unroll
      for (int ni = 0; ni < 4; ++ni) {
        f32x4 acc = {bb4[ni], bb4[ni], bb4[ni], bb4[ni]};
        acc = __builtin_amdgcn_mfma_f32_16x16x32_bf16(a[0], B4[ni][0], acc, 0, 0, 0);
        acc = __builtin_amdgcn_mfma_f32_16x16x32_bf16(a[1], B4[ni][1], acc, 0, 0, 0);
        acc = __builtin_amdgcn_mfma_f32_16x16x32_bf16(a[2], B4[ni][2], acc, 0, 0, 0);
        acc = __builtin_amdgcn_mfma_f32_16x16x32_bf16(a[3], B4[ni][3], acc, 0, 0, 0);
#pragma unroll
        for (int r = 0; r < 4; ++r)
          vmax[ni] = fmaxf(vmax[ni], acc[r]);
      }
      if (mt & 1) {
        const int sl = mt >> 1;
#pragma unroll
        for (int ni = 0; ni < 4; ++ni) {
          float v = vmax[ni];
          v = fmaxf(v, __shfl_xor(v, 16));
          v = fmaxf(v, __shfl_xor(v, 32));
          if (g == 0) {
            const int o = (4 * w + ni) * 16 + rl;
            obuf[o * 5 + sl] = v;
          }
          vmax[ni] = 0.f;
        }
      }
    }
  }
  __syncthreads();
  {
    float v[4];
#pragma unroll
    for (int j = 0; j < 4; ++j) v[j] = obuf[t * 5 + j];
    float* po = out + ((size_t)(b * 256 + t) << 10) + sbase;
    float4 v0; v0.x = v[0]; v0.y = v[1]; v0.z = v[2]; v0.w = v[3];
    *(float4*)po = v0;
  }
}

// ---------- fallback: R3 monolithic kernel (known-passing; uses linear WB4) ----------
template <bool P>
__global__ __launch_bounds__(256, 2) void rcri_main(
    const float* __restrict__ contour, const float* __restrict__ loa,
    const float* __restrict__ prev, const unsigned char* __restrict__ ws,
    const float* __restrict__ ew1, const float* __restrict__ eb1,
    const float* __restrict__ eg1, const float* __restrict__ ebeta1,
    const float* __restrict__ em1, const float* __restrict__ ev1,
    const float* __restrict__ ew2, const float* __restrict__ eb2,
    const float* __restrict__ eg2, const float* __restrict__ ebeta2,
    const float* __restrict__ em2, const float* __restrict__ ev2,
    const float* __restrict__ fw1, const float* __restrict__ fb1,
    const float* __restrict__ fg1, const float* __restrict__ fbeta1,
    const float* __restrict__ fm1, const float* __restrict__ fv1,
    const float* __restrict__ fw2, const float* __restrict__ fb2,
    const float* __restrict__ fg2, const float* __restrict__ fbeta2,
    const float* __restrict__ fm2, const float* __restrict__ fv2,
    float* __restrict__ out)
{
  __shared__ __align__(16) unsigned char smem[65536 + 9216];
  float* obuf = (float*)(smem + 65536);

  const int t = threadIdx.x;
  const int lane = t & 63;
  const int w = t >> 6;
  const int rl = lane & 15;
  const int g = lane >> 4;
  const int blk = blockIdx.x;
  const int b = blk >> 7;
  const int s_base = (blk & 127) << 3;

  const unsigned short* wb3 = (const unsigned short*)(ws + WB3);
  const unsigned short* wb4 = (const unsigned short*)(ws + WB4);
  const float* b3p = (const float*)(ws + BB3);
  const float* b4p = (const float*)(ws + BB4);
  const float* w1p = (const float*)(ws + EW1);
  const float* b1p = (const float*)(ws + EB1);
  const float* w2p = (const float*)(ws + EW2);
  const float* b2p = (const float*)(ws + EB2);

  const float2* c2 = (const float2*)contour;
  const float2* l2 = (const float2*)loa;

  auto cat_off = [](int m, int byte) { return m * 256 + (byte ^ ((m & 15) << 4)); };
  auto h3_off  = [](int m, int byte) { return 32768 + m * 256 + (byte ^ ((m & 15) << 4)); };

  for (int hh = 0; hh < 2; ++hh) {
    {
      const int m = t & 127;
      const int hf = t >> 7;
      const int sl4 = m >> 5, kk = m & 31;
      const int s = s_base + hh * 4 + sl4;
      const int ci = ci_of(s);
      const int n = (ci - 16 + kk) & (Nn - 1);

#pragma unroll
      for (int u = 0; u < 8; ++u) {
        const int c0 = hf * 32 + u * 4;
        const float* pp = prev + (size_t)(b * 64 + c0) * Nn + n;
        const float p0 = pp[0], p1 = pp[Nn], p2 = pp[2 * Nn], p3 = pp[3 * Nn];
        const unsigned int u0 = (unsigned)f2bf(p0) | ((unsigned)f2bf(p1) << 16);
        const unsigned int u1 = (unsigned)f2bf(p2) | ((unsigned)f2bf(p3) << 16);
        *(uint2*)(smem + cat_off(m, 128 + 2 * c0)) = make_uint2(u0, u1);
      }

      const float2 xi = c2[b * Nn + n];
      const float2 lx = l2[b * Nn + n];
      const float2 sp = c2[b * Nn + ci];
      const float2 lc = l2[b * Nn + ci];

      float2 xim1 = make_float2(0.f, 0.f), lxm1 = make_float2(0.f, 0.f);
      if (kk > 0) {
        const int np = (ci - 16 + kk - 1) & (Nn - 1);
        xim1 = c2[b * Nn + np];
        lxm1 = l2[b * Nn + np];
      }

      const float vx = xi.x - sp.x, vy = xi.y - sp.y;
      const float f4 = sqrtf(vx * vx + vy * vy);
      const float inv = 1.0f / (f4 + F_EPS);
      const float ux = vx * inv, uy = vy * inv;
      const float a1 = lc.x * ux + lc.y * uy;
      const float a2 = -(lx.x * ux + lx.y * uy);
      float dotp = lx.x * lc.x + lx.y * lc.y;
      float cl = fminf(fmaxf(dotp, -1.0f + F_EPS), 1.0f - F_EPS);
      const float f3o = (a1 < a2 ? 1.0f : -1.0f) * acosf(cl);

      float pux = 0.f, puy = 0.f;
      if (kk > 0) {
        const float pvx = xim1.x - sp.x, pvy = xim1.y - sp.y;
        const float pf4 = sqrtf(pvx * pvx + pvy * pvy);
        const float pinv = 1.0f / (pf4 + F_EPS);
        pux = pvx * pinv; puy = pvy * pinv;
      }
      const float vpx = (kk > 0) ? (xi.x - xim1.x) : 0.0f;
      const float vpy = (kk > 0) ? (xi.y - xim1.y) : 0.0f;
      const float f8 = sqrtf(vpx * vpx + vpy * vpy);
      const float invp = 1.0f / (f8 + F_EPS);
      const float upx = vpx * invp, upy = vpy * invp;
      const float a4 = upx * lx.x + upy * lx.y;
      const float a5 = upx * lxm1.x + upy * lxm1.y;
      float dotp2 = lx.x * lxm1.x + lx.y * lxm1.y;
      float cl2 = fminf(fmaxf(dotp2, -1.0f + F_EPS), 1.0f - F_EPS);
      const float f7o = (a4 < a5 ? 1.0f : -1.0f) * acosf(cl2);
      float du = ux * pux + uy * puy;
      float cl3 = fminf(fmaxf(du, -1.0f + F_EPS), 1.0f - F_EPS);
      const float d2 = acosf(cl3);

      const float rif[8] = {f4, d2, a1, a2, f3o, a4, a5, f7o};

      float h1v[32];
#pragma unroll
      for (int o = 0; o < 32; ++o) {
        float acc;
        if (P) {
          acc = b1p[o];
#pragma unroll
          for (int c = 0; c < 8; ++c) acc += w1p[o * 8 + c] * rif[c];
        } else {
          float a0 = 0.f;
#pragma unroll
          for (int c = 0; c < 8; ++c) a0 += ew1[o * 8 + c] * rif[c];
          const float sc = eg1[o] * rsqrtf(ev1[o] + F_BN_EPS);
          acc = (a0 + eb1[o] - em1[o]) * sc + ebeta1[o];
        }
        h1v[o] = fmaxf(acc, 0.f);
      }

#pragma unroll
      for (int i = 0; i < 8; ++i) {
        float yv[4];
#pragma unroll
        for (int j = 0; j < 4; ++j) {
          const int o = hf * 32 + i * 4 + j;
          float acc;
          if (P) {
            acc = b2p[o];
#pragma unroll
            for (int c = 0; c < 32; ++c) acc += w2p[o * 32 + c] * h1v[c];
          } else {
            float a0 = 0.f;
#pragma unroll
            for (int c = 0; c < 32; ++c) a0 += ew2[o * 32 + c] * h1v[c];
            const float sc = eg2[o] * rsqrtf(ev2[o] + F_BN_EPS);
            acc = (a0 + eb2[o] - em2[o]) * sc + ebeta2[o];
          }
          yv[j] = fmaxf(acc, 0.f);
        }
        const unsigned int u0 = (unsigned)f2bf(yv[0]) | ((unsigned)f2bf(yv[1]) << 16);
        const unsigned int u1 = (unsigned)f2bf(yv[2]) | ((unsigned)f2bf(yv[3]) << 16);
        *(uint2*)(smem + cat_off(m, 64 * hf + 8 * i)) = make_uint2(u0, u1);
      }
    }
    __syncthreads();

    {
      s16x8 B3[2][4];
      float bb3[2];
#pragma unroll
      for (int i = 0; i < 2; ++i) {
        const int o = (2 * w + i) * 16 + rl;
        if (P) {
#pragma unroll
          for (int kt = 0; kt < 4; ++kt)
            B3[i][kt] = *(const s16x8*)(wb3 + o * 128 + kt * 32 + 8 * g);
          bb3[i] = b3p[o];
        } else {
          const float sc = fg1[o] * rsqrtf(fv1[o] + F_BN_EPS);
#pragma unroll
          for (int kt = 0; kt < 4; ++kt)
            B3[i][kt] = pack_scaled(fw1 + o * 128 + kt * 32 + 8 * g, sc);
          bb3[i] = (fb1[o] - fm1[o]) * sc + fbeta1[o];
        }
      }
      for (int mt = 0; mt < 8; ++mt) {
        const int row = mt * 16 + rl;
        s16x8 a[4];
#pragma unroll
        for (int kt = 0; kt < 4; ++kt)
          a[kt] = __builtin_bit_cast(s16x8, *(const uint4*)(smem + cat_off(row, kt * 64 + 16 * g)));
#pragma unroll
        for (int i = 0; i < 2; ++i) {
          f32x4 acc = {0.f, 0.f, 0.f, 0.f};
          acc = __builtin_amdgcn_mfma_f32_16x16x32_bf16(a[0], B3[i][0], acc, 0, 0, 0);
          acc = __builtin_amdgcn_mfma_f32_16x16x32_bf16(a[1], B3[i][1], acc, 0, 0, 0);
          acc = __builtin_amdgcn_mfma_f32_16x16x32_bf16(a[2], B3[i][2], acc, 0, 0, 0);
          acc = __builtin_amdgcn_mfma_f32_16x16x32_bf16(a[3], B3[i][3], acc, 0, 0, 0);
          const int o = (2 * w + i) * 16 + rl;
#pragma unroll
          for (int r = 0; r < 4; ++r) {
            const float y = fmaxf(acc[r] + bb3[i], 0.f);
            *(unsigned short*)(smem + h3_off(mt * 16 + 4 * g + r, 2 * o)) = f2bf(y);
          }
        }
      }
    }
    __syncthreads();

#pragma unroll
    for (int nip = 0; nip < 2; ++nip) {
      s16x8 B4[2][4];
      float bb4[2];
#pragma unroll
      for (int q = 0; q < 2; ++q) {
        const int o = (4 * w + nip * 2 + q) * 16 + rl;
        if (P) {
#pragma unroll
          for (int kt = 0; kt < 4; ++kt)
            B4[q][kt] = *(const s16x8*)(wb4 + o * 128 + kt * 32 + 8 * g);
          bb4[q] = b4p[o];
        } else {
          const float sc = fg2[o] * rsqrtf(fv2[o] + F_BN_EPS);
#pragma unroll
          for (int kt = 0; kt < 4; ++kt)
            B4[q][kt] = pack_scaled(fw2 + o * 128 + kt * 32 + 8 * g, sc);
          bb4[q] = (fb2[o] - fm2[o]) * sc + fbeta2[o];
        }
      }
      float vm[2] = {-INFINITY, -INFINITY};
      for (int mt = 0; mt < 8; ++mt) {
        const int row = mt * 16 + rl;
        s16x8 a[4];
#pragma unroll
        for (int kt = 0; kt < 4; ++kt)
          a[kt] = __builtin_bit_cast(s16x8, *(const uint4*)(smem + h3_off(row, kt * 64 + 16 * g)));
#pragma unroll
        for (int q = 0; q < 2; ++q) {
          f32x4 acc = {0.f, 0.f, 0.f, 0.f};
          acc = __builtin_amdgcn_mfma_f32_16x16x32_bf16(a[0], B4[q][0], acc, 0, 0, 0);
          acc = __builtin_amdgcn_mfma_f32_16x16x32_bf16(a[1], B4[q][1], acc, 0, 0, 0);
          acc = __builtin_amdgcn_mfma_f32_16x16x32_bf16(a[2], B4[q][2], acc, 0, 0, 0);
          acc = __builtin_amdgcn_mfma_f32_16x16x32_bf16(a[3], B4[q][3], acc, 0, 0, 0);
#pragma unroll
          for (int r = 0; r < 4; ++r)
            vm[q] = fmaxf(vm[q], fmaxf(acc[r] + bb4[q], 0.f));
        }
        if (mt & 1) {
          const int sl = hh * 4 + (mt >> 1);
#pragma unroll
          for (int q = 0; q < 2; ++q) {
            float v = vm[q];
            v = fmaxf(v, __shfl_xor(v, 16));
            v = fmaxf(v, __shfl_xor(v, 32));
            if (g == 0) {
              const int o = (4 * w + nip * 2 + q) * 16 + rl;
              obuf[o * 9 + sl] = v;
            }
            vm[q] = -INFINITY;
          }
        }
      }
    }
  }

  __syncthreads();
  {
    float v[8];
#pragma unroll
    for (int j = 0; j < 8; ++j) v[j] = obuf[t * 9 + j];
    float* po = out + ((size_t)(b * 256 + t) << 10) + s_base;
    float4 v0; v0.x = v[0]; v0.y = v[1]; v0.z = v[2]; v0.w = v[3];
    float4 v1; v1.x = v[4]; v1.y = v[5]; v1.z = v[6]; v1.w = v[7];
    *(float4*)po = v0;
    *(float4*)(po + 4) = v1;
  }
}

}  // namespace

extern "C" void kernel_launch(void* const* d_in, const int* in_sizes, int n_in,
                              void* d_out, int out_size, void* d_ws, size_t ws_size,
                              hipStream_t stream) {
  (void)in_sizes; (void)n_in; (void)out_size;

  const float* contour = (const float*)d_in[0];
  const float* loa     = (const float*)d_in[1];
  const float* prev    = (const float*)d_in[2];
  const float* ew1 = (const float*)d_in[3];
  const float* eb1 = (const float*)d_in[4];
  const float* eg1 = (const float*)d_in[5];
  const float* ebeta1 = (const float*)d_in[6];
  const float* em1 = (const float*)d_in[7];
  const float* ev1 = (const float*)d_in[8];
  const float* ew2 = (const float*)d_in[9];
  const float* eb2 = (const float*)d_in[10];
  const float* eg2 = (const float*)d_in[11];
  const float* ebeta2 = (const float*)d_in[12];
  const float* em2 = (const float*)d_in[13];
  const float* ev2 = (const float*)d_in[14];
  const float* fw1 = (const float*)d_in[15];
  const float* fb1 = (const float*)d_in[16];
  const float* fg1 = (const float*)d_in[17];
  const float* fbeta1 = (const float*)d_in[18];
  const float* fm1 = (const float*)d_in[19];
  const float* fv1 = (const float*)d_in[20];
  const float* fw2 = (const float*)d_in[21];
  const float* fb2 = (const float*)d_in[22];
  const float* fg2 = (const float*)d_in[23];
  const float* fbeta2 = (const float*)d_in[24];
  const float* fm2 = (const float*)d_in[25];
  const float* fv2 = (const float*)d_in[26];

  float* out = (float*)d_out;
  unsigned char* ws = (unsigned char*)d_ws;

  if (ws && ws_size >= WS_BIG) {
    rcri_prep<<<dim3(203), dim3(256), 0, stream>>>(
        ew1, eb1, eg1, ebeta1, em1, ev1, ew2, eb2, eg2, ebeta2, em2, ev2,
        fw1, fb1, fg1, fbeta1, fm1, fv1, fw2, fb2, fg2, fbeta2, fm2, fv2, ws);
    rcri_prep2<<<dim3(128), dim3(256), 0, stream>>>(fw2, fg2, fv2, ws);
    rcri_tpose<<<dim3(512), dim3(256), 0, stream>>>(prev, ws);
    rcri_k1p<<<dim3(1024), dim3(256), 0, stream>>>(contour, loa, ws);
    rcri_k23<<<dim3(2048), dim3(256), 0, stream>>>(ws, out);
  } else if (ws && ws_size >= WS_NEED) {
    rcri_prep<<<dim3(203), dim3(256), 0, stream>>>(
        ew1, eb1, eg1, ebeta1, em1, ev1, ew2, eb2, eg2, ebeta2, em2, ev2,
        fw1, fb1, fg1, fbeta1, fm1, fv1, fw2, fb2, fg2, fbeta2, fm2, fv2, ws);
    rcri_main<true><<<dim3(1024), dim3(256), 0, stream>>>(
        contour, loa, prev, ws,
        ew1, eb1, eg1, ebeta1, em1, ev1, ew2, eb2, eg2, ebeta2, em2, ev2,
        fw1, fb1, fg1, fbeta1, fm1, fv1, fw2, fb2, fg2, fbeta2, fm2, fv2, out);
  } else {
    rcri_main<false><<<dim3(1024), dim3(256), 0, stream>>>(
        contour, loa, prev, ws,
        ew1, eb1, eg1, ebeta1, em1, ev1, ew2, eb2, eg2, ebeta2, em2, ev2,
        fw1, fb1, fg1, fbeta1, fm1, fv1, fw2, fb2, fg2, fbeta2, fm2, fv2, out);
  }
}

// Round 16
// 91.812 us; speedup vs baseline: 1.3037x; 1.3037x over previous
//
#include <hip/hip_runtime.h>
#include <math.h>

namespace {

constexpr int Nn = 8192;   // N
constexpr int Ss = 1024;   // S
constexpr float F_EPS = 1e-7f;
constexpr float F_BN_EPS = 1e-5f;

typedef __attribute__((ext_vector_type(8))) short s16x8;   // 8 bf16 = 4 VGPR
typedef __attribute__((ext_vector_type(4))) float f32x4;   // MFMA acc

// ---- d_ws layout (bytes) ----
constexpr int WB3 = 0;            // bf16 [128][128] conv3 weights, BN-folded (linear k)
constexpr int WB4 = 32768;        // bf16 [256][128] conv4 weights, BN-folded (linear k; fallback)
constexpr int BB3 = 98304;        // f32 [128]
constexpr int BB4 = 98816;        // f32 [256]
constexpr int EW1 = 99840;        // f32 [32][8]
constexpr int EB1 = 100864;       // f32 [32]
constexpr int EW2 = 100992;       // f32 [64][32]
constexpr int EB2 = 109184;       // f32 [64]
constexpr size_t WS_NEED = 109440;

// big-workspace path
constexpr size_t CATO = 131072;                       // cat[262144][64] bf16 = 32MB
constexpr size_t PVT  = CATO + 33554432ull;           // prevT[8][8192][64] bf16 = 8MB
constexpr size_t WB4P = PVT + 8388608ull;             // bf16 [256][128] conv4 weights, k sigma-permuted
constexpr size_t WS_BIG = WB4P + 65536ull;

__device__ inline unsigned short f2bf(float f) {  // RNE f32 -> bf16
  unsigned int u = __builtin_bit_cast(unsigned int, f);
  u += 0x7fffu + ((u >> 16) & 1u);
  return (unsigned short)(u >> 16);
}

__device__ inline s16x8 pack_scaled(const float* __restrict__ p, float sc) {
  const float4 w0 = *(const float4*)p;
  const float4 w1 = *(const float4*)(p + 4);
  s16x8 r;
  r[0] = (short)f2bf(w0.x * sc); r[1] = (short)f2bf(w0.y * sc);
  r[2] = (short)f2bf(w0.z * sc); r[3] = (short)f2bf(w0.w * sc);
  r[4] = (short)f2bf(w1.x * sc); r[5] = (short)f2bf(w1.y * sc);
  r[6] = (short)f2bf(w1.z * sc); r[7] = (short)f2bf(w1.w * sc);
  return r;
}

// A-fragment from prev[b][c][n] (fallback path only; validated R1)
__device__ inline s16x8 prev_frag(const float* __restrict__ prev, int b, int cbase, int n) {
  const float* p = prev + (size_t)(b * 64 + cbase) * Nn + n;
  s16x8 r;
#pragma unroll
  for (int j = 0; j < 8; ++j) r[j] = (short)f2bf(p[j * Nn]);
  return r;
}

__device__ inline int ci_of(int s) {
  return (s == Ss - 1) ? (Nn - 1) : (int)(long long)((double)s * (8191.0 / 1023.0));
}

// ---------- prep: fold BN into weights/biases, bf16-convert GEMM weights ----------
// Extended with the sigma-permuted WB4P fill (formerly prep2) at the tail of the chain.
__global__ __launch_bounds__(256) void rcri_prep(
    const float* __restrict__ ew1, const float* __restrict__ eb1,
    const float* __restrict__ eg1, const float* __restrict__ ebeta1,
    const float* __restrict__ em1, const float* __restrict__ ev1,
    const float* __restrict__ ew2, const float* __restrict__ eb2,
    const float* __restrict__ eg2, const float* __restrict__ ebeta2,
    const float* __restrict__ em2, const float* __restrict__ ev2,
    const float* __restrict__ fw1, const float* __restrict__ fb1,
    const float* __restrict__ fg1, const float* __restrict__ fbeta1,
    const float* __restrict__ fm1, const float* __restrict__ fv1,
    const float* __restrict__ fw2, const float* __restrict__ fb2,
    const float* __restrict__ fg2, const float* __restrict__ fbeta2,
    const float* __restrict__ fm2, const float* __restrict__ fv2,
    unsigned char* __restrict__ ws)
{
  const int i = blockIdx.x * 256 + threadIdx.x;
  if (i < 16384) {
    const int o = i >> 7;
    const float sc = fg1[o] * rsqrtf(fv1[o] + F_BN_EPS);
    ((unsigned short*)(ws + WB3))[i] = f2bf(fw1[i] * sc);
    return;
  }
  int j = i - 16384;
  if (j < 32768) {
    const int o = j >> 7;
    const float sc = fg2[o] * rsqrtf(fv2[o] + F_BN_EPS);
    ((unsigned short*)(ws + WB4))[j] = f2bf(fw2[j] * sc);
    return;
  }
  j -= 32768;
  if (j < 128) {
    const float sc = fg1[j] * rsqrtf(fv1[j] + F_BN_EPS);
    ((float*)(ws + BB3))[j] = (fb1[j] - fm1[j]) * sc + fbeta1[j];
    return;
  }
  j -= 128;
  if (j < 256) {
    const float sc = fg2[j] * rsqrtf(fv2[j] + F_BN_EPS);
    ((float*)(ws + BB4))[j] = (fb2[j] - fm2[j]) * sc + fbeta2[j];
    return;
  }
  j -= 256;
  if (j < 256) {
    const int o = j >> 3;
    const float sc = eg1[o] * rsqrtf(ev1[o] + F_BN_EPS);
    ((float*)(ws + EW1))[j] = ew1[j] * sc;
    return;
  }
  j -= 256;
  if (j < 32) {
    const float sc = eg1[j] * rsqrtf(ev1[j] + F_BN_EPS);
    ((float*)(ws + EB1))[j] = (eb1[j] - em1[j]) * sc + ebeta1[j];
    return;
  }
  j -= 32;
  if (j < 2048) {
    const int o = j >> 5;
    const float sc = eg2[o] * rsqrtf(ev2[o] + F_BN_EPS);
    ((float*)(ws + EW2))[j] = ew2[j] * sc;
    return;
  }
  j -= 2048;
  if (j < 64) {
    const float sc = eg2[j] * rsqrtf(ev2[j] + F_BN_EPS);
    ((float*)(ws + EB2))[j] = (eb2[j] - em2[j]) * sc + ebeta2[j];
    return;
  }
  j -= 64;
  if (j < 32768) {  // WB4P: sigma-permuted conv4 weights (formerly prep2)
    const int o = j >> 7;
    const int jk = j & 127;
    const int c = 32 * (jk >> 5) + 16 * (jk & 1) + ((jk & 31) >> 1);
    const float sc = fg2[o] * rsqrtf(fv2[o] + F_BN_EPS);
    ((unsigned short*)(ws + WB4P))[j] = f2bf(fw2[o * 128 + c] * sc);
  }
}

// ---------- tpose: prev[b][c][n] f32 -> prevT[b][n][64] bf16 ----------
__global__ __launch_bounds__(256) void rcri_tpose(
    const float* __restrict__ prev, unsigned char* __restrict__ ws)
{
  __shared__ unsigned short tile[128 * 72];
  const int t = threadIdx.x;
  const int b = blockIdx.x >> 6;
  const int n0 = (blockIdx.x & 63) * 128;
  const int nloc = t & 127;
  const int chalf = t >> 7;

#pragma unroll
  for (int it = 0; it < 32; ++it) {
    const int c = it * 2 + chalf;
    const float v = prev[(size_t)(b * 64 + c) * Nn + n0 + nloc];
    tile[nloc * 72 + c] = f2bf(v);
  }
  __syncthreads();

#pragma unroll
  for (int it = 0; it < 4; ++it) {
    const int idx = it * 256 + t;
    const int rn = idx >> 3;
    const int cc = idx & 7;
    const uint4 v = *(const uint4*)((const unsigned char*)tile + rn * 144 + cc * 16);
    *(uint4*)(ws + PVT + (size_t)(b * Nn + n0 + rn) * 128 + cc * 16) = v;
  }
}

// ---------- K1f2: features + conv1 + conv2 (f32, LDS weights; R12-validated best) ----------
__global__ __launch_bounds__(256) void rcri_k1f2(
    const float* __restrict__ contour, const float* __restrict__ loa,
    unsigned char* __restrict__ ws)
{
  __shared__ float wlds[2400];   // ew1'[32][8] | eb1'[32] | ew2'[64][32] | eb2'[64]
  __shared__ __align__(16) unsigned char cstage[128 * 144];  // [row][64ch bf16], 144B pitch

  const int t = threadIdx.x;
  for (int j = t; j < 2400; j += 256) wlds[j] = ((const float*)(ws + EW1))[j];

  const int r = t & 127;
  const int hf = t >> 7;
  const int row = blockIdx.x * 128 + r;
  const int b = row >> 15;
  const int s = (row >> 5) & 1023;
  const int kk = row & 31;
  const int ci = ci_of(s);
  const int n = (ci - 16 + kk) & (Nn - 1);

  const float2* c2 = (const float2*)contour;
  const float2* l2 = (const float2*)loa;

  const float2 xi = c2[b * Nn + n];
  const float2 lx = l2[b * Nn + n];
  const float2 sp = c2[b * Nn + ci];
  const float2 lc = l2[b * Nn + ci];

  float2 xim1 = make_float2(0.f, 0.f), lxm1 = make_float2(0.f, 0.f);
  if (kk > 0) {
    const int np = (ci - 16 + kk - 1) & (Nn - 1);
    xim1 = c2[b * Nn + np];
    lxm1 = l2[b * Nn + np];
  }

  const float vx = xi.x - sp.x, vy = xi.y - sp.y;
  const float f4 = sqrtf(vx * vx + vy * vy);
  const float inv = 1.0f / (f4 + F_EPS);
  const float ux = vx * inv, uy = vy * inv;
  const float a1 = lc.x * ux + lc.y * uy;
  const float a2 = -(lx.x * ux + lx.y * uy);
  float dotp = lx.x * lc.x + lx.y * lc.y;
  float cl = fminf(fmaxf(dotp, -1.0f + F_EPS), 1.0f - F_EPS);
  const float f3o = (a1 < a2 ? 1.0f : -1.0f) * acosf(cl);

  float pux = 0.f, puy = 0.f;
  if (kk > 0) {
    const float pvx = xim1.x - sp.x, pvy = xim1.y - sp.y;
    const float pf4 = sqrtf(pvx * pvx + pvy * pvy);
    const float pinv = 1.0f / (pf4 + F_EPS);
    pux = pvx * pinv; puy = pvy * pinv;
  }
  const float vpx = (kk > 0) ? (xi.x - xim1.x) : 0.0f;
  const float vpy = (kk > 0) ? (xi.y - xim1.y) : 0.0f;
  const float f8 = sqrtf(vpx * vpx + vpy * vpy);
  const float invp = 1.0f / (f8 + F_EPS);
  const float upx = vpx * invp, upy = vpy * invp;
  const float a4 = upx * lx.x + upy * lx.y;
  const float a5 = upx * lxm1.x + upy * lxm1.y;
  float dotp2 = lx.x * lxm1.x + lx.y * lxm1.y;
  float cl2 = fminf(fmaxf(dotp2, -1.0f + F_EPS), 1.0f - F_EPS);
  const float f7o = (a4 < a5 ? 1.0f : -1.0f) * acosf(cl2);
  float du = ux * pux + uy * puy;
  float cl3 = fminf(fmaxf(du, -1.0f + F_EPS), 1.0f - F_EPS);
  const float d2 = acosf(cl3);

  __syncthreads();  // wlds ready

  // conv1: 8 -> 32 (full per thread; conv2 needs all 32 inputs)
  float h1v[32];
#pragma unroll
  for (int o = 0; o < 32; ++o) {
    const float4 w0 = *(const float4*)(wlds + o * 8);
    const float4 w1 = *(const float4*)(wlds + o * 8 + 4);
    float acc = wlds[256 + o]
      + w0.x * f4  + w0.y * d2  + w0.z * a1  + w0.w * a2
      + w1.x * f3o + w1.y * a4  + w1.z * a5  + w1.w * f7o;
    h1v[o] = fmaxf(acc, 0.f);
  }

  // conv2: this thread's 32 of 64 outputs -> bf16 cstage
#pragma unroll
  for (int grp = 0; grp < 4; ++grp) {
    unsigned int uu[4];
#pragma unroll
    for (int q = 0; q < 4; ++q) {
      float y2[2];
#pragma unroll
      for (int jj = 0; jj < 2; ++jj) {
        const int o = hf * 32 + grp * 8 + q * 2 + jj;
        float acc = wlds[2336 + o];
#pragma unroll
        for (int c4 = 0; c4 < 8; ++c4) {
          const float4 ww = *(const float4*)(wlds + 288 + o * 32 + c4 * 4);
          acc += ww.x * h1v[c4 * 4 + 0] + ww.y * h1v[c4 * 4 + 1]
               + ww.z * h1v[c4 * 4 + 2] + ww.w * h1v[c4 * 4 + 3];
        }
        y2[jj] = fmaxf(acc, 0.f);
      }
      uu[q] = (unsigned)f2bf(y2[0]) | ((unsigned)f2bf(y2[1]) << 16);
    }
    *(uint4*)(cstage + r * 144 + hf * 64 + grp * 16) = make_uint4(uu[0], uu[1], uu[2], uu[3]);
  }
  __syncthreads();

  // coalesced write-out: 128 rows x 128B
#pragma unroll
  for (int it = 0; it < 4; ++it) {
    const int idx = it * 256 + t;
    const int rr = idx >> 3;
    const int cc = idx & 7;
    const uint4 v = *(const uint4*)(cstage + rr * 144 + cc * 16);
    *(uint4*)(ws + CATO + (size_t)(blockIdx.x * 128 + rr) * 128 + cc * 16) = v;
  }
}

// ---------- K23: bulk-staged conv3 (h3 aliased onto stage) + conv4 + max (R12 verbatim) ----------
__global__ __launch_bounds__(256) void rcri_k23(
    const unsigned char* __restrict__ ws, float* __restrict__ out)
{
  __shared__ __align__(16) unsigned char stage[32768];
  __shared__ float obuf[256 * 5];

  const int t = threadIdx.x;
  const int lane = t & 63;
  const int w = t >> 6;
  const int rl = lane & 15;
  const int g = lane >> 4;
  const int rows0 = blockIdx.x * 128;   // 4 samples
  const int b = blockIdx.x >> 8;
  const int sbase = (blockIdx.x & 255) * 4;

  const unsigned char* catp = ws + CATO + (size_t)rows0 * 128;
  const unsigned char* pvtp = ws + PVT + (size_t)b * Nn * 128;

  // ---- bulk stage: 8 loads in flight per thread, then LDS writes ----
  {
    const int slot = t & 15;
    uint4 v[8];
#pragma unroll
    for (int i = 0; i < 8; ++i) {
      const int row = i * 16 + (t >> 4);
      const int c = slot ^ (row & 15);
      const unsigned char* src;
      if (c < 8) {
        src = catp + (size_t)row * 128 + c * 16;
      } else {
        const int rg = rows0 + row;
        const int s = (rg >> 5) & 1023;
        const int kk = rg & 31;
        const int n = (ci_of(s) - 16 + kk) & (Nn - 1);
        src = pvtp + (size_t)n * 128 + (c - 8) * 16;
      }
      v[i] = *(const uint4*)src;
    }
#pragma unroll
    for (int i = 0; i < 8; ++i)
      *(uint4*)(stage + i * 4096 + t * 16) = v[i];
  }
  __syncthreads();

  // ---- conv3: 128 -> 128 from staged LDS; h3 written IN PLACE over stage rows ----
  {
    const unsigned short* wb3 = (const unsigned short*)(ws + WB3);
    const float* b3p = (const float*)(ws + BB3);
    s16x8 B3[2][4];
    float bb3[2];
#pragma unroll
    for (int i = 0; i < 2; ++i) {
      const int o = (2 * w + i) * 16 + rl;
#pragma unroll
      for (int kt = 0; kt < 4; ++kt)
        B3[i][kt] = *(const s16x8*)(wb3 + o * 128 + kt * 32 + 8 * g);
      bb3[i] = b3p[o];
    }
    for (int mt = 0; mt < 8; ++mt) {
      const int rowl = mt * 16 + rl;
      const int sw = (rowl & 15) << 4;
      const s16x8 a0 = __builtin_bit_cast(s16x8, *(const uint4*)(stage + rowl * 256 + ((16 * (g))      ^ sw)));
      const s16x8 a1 = __builtin_bit_cast(s16x8, *(const uint4*)(stage + rowl * 256 + ((16 * (4 + g))  ^ sw)));
      const s16x8 a2 = __builtin_bit_cast(s16x8, *(const uint4*)(stage + rowl * 256 + ((16 * (8 + g))  ^ sw)));
      const s16x8 a3 = __builtin_bit_cast(s16x8, *(const uint4*)(stage + rowl * 256 + ((16 * (12 + g)) ^ sw)));

      __syncthreads();  // all waves' reads of this mt's rows complete before in-place writes

      f32x4 acc0 = {bb3[0], bb3[0], bb3[0], bb3[0]};
      f32x4 acc1 = {bb3[1], bb3[1], bb3[1], bb3[1]};
      acc0 = __builtin_amdgcn_mfma_f32_16x16x32_bf16(a0, B3[0][0], acc0, 0, 0, 0);
      acc0 = __builtin_amdgcn_mfma_f32_16x16x32_bf16(a1, B3[0][1], acc0, 0, 0, 0);
      acc0 = __builtin_amdgcn_mfma_f32_16x16x32_bf16(a2, B3[0][2], acc0, 0, 0, 0);
      acc0 = __builtin_amdgcn_mfma_f32_16x16x32_bf16(a3, B3[0][3], acc0, 0, 0, 0);
      acc1 = __builtin_amdgcn_mfma_f32_16x16x32_bf16(a0, B3[1][0], acc1, 0, 0, 0);
      acc1 = __builtin_amdgcn_mfma_f32_16x16x32_bf16(a1, B3[1][1], acc1, 0, 0, 0);
      acc1 = __builtin_amdgcn_mfma_f32_16x16x32_bf16(a2, B3[1][2], acc1, 0, 0, 0);
      acc1 = __builtin_amdgcn_mfma_f32_16x16x32_bf16(a3, B3[1][3], acc1, 0, 0, 0);

#pragma unroll
      for (int r = 0; r < 4; ++r) {
        const int row2 = mt * 16 + 4 * g + r;
        const unsigned u = (unsigned)f2bf(fmaxf(acc0[r], 0.f))
                         | ((unsigned)f2bf(fmaxf(acc1[r], 0.f)) << 16);
        *(unsigned int*)(stage + row2 * 256 + ((64 * w + 4 * rl) ^ ((row2 & 15) << 4))) = u;
      }
    }
  }
  __syncthreads();

  // ---- conv4: 128 -> 256 (sigma-permuted weights) + relu-folded max over k ----
  {
    const unsigned short* wb4p = (const unsigned short*)(ws + WB4P);
    const float* b4p = (const float*)(ws + BB4);
    s16x8 B4[4][4];
    float bb4[4];
#pragma unroll
    for (int ni = 0; ni < 4; ++ni) {
      const int o = (4 * w + ni) * 16 + rl;
#pragma unroll
      for (int kt = 0; kt < 4; ++kt)
        B4[ni][kt] = *(const s16x8*)(wb4p + o * 128 + kt * 32 + 8 * g);
      bb4[ni] = b4p[o];
    }
    float vmax[4] = {0.f, 0.f, 0.f, 0.f};   // relu folded: max(0, max_k y)
#pragma unroll 2
    for (int mt = 0; mt < 8; ++mt) {
      const int rowl = mt * 16 + rl;
      s16x8 a[4];
#pragma unroll
      for (int kt = 0; kt < 4; ++kt)
        a[kt] = __builtin_bit_cast(s16x8,
            *(const uint4*)(stage + rowl * 256 + ((kt * 64 + 16 * g) ^ ((rowl & 15) << 4))));
#pragma unroll
      for (int ni = 0; ni < 4; ++ni) {
        f32x4 acc = {bb4[ni], bb4[ni], bb4[ni], bb4[ni]};
        acc = __builtin_amdgcn_mfma_f32_16x16x32_bf16(a[0], B4[ni][0], acc, 0, 0, 0);
        acc = __builtin_amdgcn_mfma_f32_16x16x32_bf16(a[1], B4[ni][1], acc, 0, 0, 0);
        acc = __builtin_amdgcn_mfma_f32_16x16x32_bf16(a[2], B4[ni][2], acc, 0, 0, 0);
        acc = __builtin_amdgcn_mfma_f32_16x16x32_bf16(a[3], B4[ni][3], acc, 0, 0, 0);
#pragma unroll
        for (int r = 0; r < 4; ++r)
          vmax[ni] = fmaxf(vmax[ni], acc[r]);
      }
      if (mt & 1) {
        const int sl = mt >> 1;
#pragma unroll
        for (int ni = 0; ni < 4; ++ni) {
          float v = vmax[ni];
          v = fmaxf(v, __shfl_xor(v, 16));
          v = fmaxf(v, __shfl_xor(v, 32));
          if (g == 0) {
            const int o = (4 * w + ni) * 16 + rl;
            obuf[o * 5 + sl] = v;
          }
          vmax[ni] = 0.f;
        }
      }
    }
  }
  __syncthreads();
  {
    float v[4];
#pragma unroll
    for (int j = 0; j < 4; ++j) v[j] = obuf[t * 5 + j];
    float* po = out + ((size_t)(b * 256 + t) << 10) + sbase;
    float4 v0; v0.x = v[0]; v0.y = v[1]; v0.z = v[2]; v0.w = v[3];
    *(float4*)po = v0;
  }
}

// ---------- fallback: R3 monolithic kernel (known-passing; uses linear WB4) ----------
template <bool P>
__global__ __launch_bounds__(256, 2) void rcri_main(
    const float* __restrict__ contour, const float* __restrict__ loa,
    const float* __restrict__ prev, const unsigned char* __restrict__ ws,
    const float* __restrict__ ew1, const float* __restrict__ eb1,
    const float* __restrict__ eg1, const float* __restrict__ ebeta1,
    const float* __restrict__ em1, const float* __restrict__ ev1,
    const float* __restrict__ ew2, const float* __restrict__ eb2,
    const float* __restrict__ eg2, const float* __restrict__ ebeta2,
    const float* __restrict__ em2, const float* __restrict__ ev2,
    const float* __restrict__ fw1, const float* __restrict__ fb1,
    const float* __restrict__ fg1, const float* __restrict__ fbeta1,
    const float* __restrict__ fm1, const float* __restrict__ fv1,
    const float* __restrict__ fw2, const float* __restrict__ fb2,
    const float* __restrict__ fg2, const float* __restrict__ fbeta2,
    const float* __restrict__ fm2, const float* __restrict__ fv2,
    float* __restrict__ out)
{
  __shared__ __align__(16) unsigned char smem[65536 + 9216];
  float* obuf = (float*)(smem + 65536);

  const int t = threadIdx.x;
  const int lane = t & 63;
  const int w = t >> 6;
  const int rl = lane & 15;
  const int g = lane >> 4;
  const int blk = blockIdx.x;
  const int b = blk >> 7;
  const int s_base = (blk & 127) << 3;

  const unsigned short* wb3 = (const unsigned short*)(ws + WB3);
  const unsigned short* wb4 = (const unsigned short*)(ws + WB4);
  const float* b3p = (const float*)(ws + BB3);
  const float* b4p = (const float*)(ws + BB4);
  const float* w1p = (const float*)(ws + EW1);
  const float* b1p = (const float*)(ws + EB1);
  const float* w2p = (const float*)(ws + EW2);
  const float* b2p = (const float*)(ws + EB2);

  const float2* c2 = (const float2*)contour;
  const float2* l2 = (const float2*)loa;

  auto cat_off = [](int m, int byte) { return m * 256 + (byte ^ ((m & 15) << 4)); };
  auto h3_off  = [](int m, int byte) { return 32768 + m * 256 + (byte ^ ((m & 15) << 4)); };

  for (int hh = 0; hh < 2; ++hh) {
    {
      const int m = t & 127;
      const int hf = t >> 7;
      const int sl4 = m >> 5, kk = m & 31;
      const int s = s_base + hh * 4 + sl4;
      const int ci = ci_of(s);
      const int n = (ci - 16 + kk) & (Nn - 1);

#pragma unroll
      for (int u = 0; u < 8; ++u) {
        const int c0 = hf * 32 + u * 4;
        const float* pp = prev + (size_t)(b * 64 + c0) * Nn + n;
        const float p0 = pp[0], p1 = pp[Nn], p2 = pp[2 * Nn], p3 = pp[3 * Nn];
        const unsigned int u0 = (unsigned)f2bf(p0) | ((unsigned)f2bf(p1) << 16);
        const unsigned int u1 = (unsigned)f2bf(p2) | ((unsigned)f2bf(p3) << 16);
        *(uint2*)(smem + cat_off(m, 128 + 2 * c0)) = make_uint2(u0, u1);
      }

      const float2 xi = c2[b * Nn + n];
      const float2 lx = l2[b * Nn + n];
      const float2 sp = c2[b * Nn + ci];
      const float2 lc = l2[b * Nn + ci];

      float2 xim1 = make_float2(0.f, 0.f), lxm1 = make_float2(0.f, 0.f);
      if (kk > 0) {
        const int np = (ci - 16 + kk - 1) & (Nn - 1);
        xim1 = c2[b * Nn + np];
        lxm1 = l2[b * Nn + np];
      }

      const float vx = xi.x - sp.x, vy = xi.y - sp.y;
      const float f4 = sqrtf(vx * vx + vy * vy);
      const float inv = 1.0f / (f4 + F_EPS);
      const float ux = vx * inv, uy = vy * inv;
      const float a1 = lc.x * ux + lc.y * uy;
      const float a2 = -(lx.x * ux + lx.y * uy);
      float dotp = lx.x * lc.x + lx.y * lc.y;
      float cl = fminf(fmaxf(dotp, -1.0f + F_EPS), 1.0f - F_EPS);
      const float f3o = (a1 < a2 ? 1.0f : -1.0f) * acosf(cl);

      float pux = 0.f, puy = 0.f;
      if (kk > 0) {
        const float pvx = xim1.x - sp.x, pvy = xim1.y - sp.y;
        const float pf4 = sqrtf(pvx * pvx + pvy * pvy);
        const float pinv = 1.0f / (pf4 + F_EPS);
        pux = pvx * pinv; puy = pvy * pinv;
      }
      const float vpx = (kk > 0) ? (xi.x - xim1.x) : 0.0f;
      const float vpy = (kk > 0) ? (xi.y - xim1.y) : 0.0f;
      const float f8 = sqrtf(vpx * vpx + vpy * vpy);
      const float invp = 1.0f / (f8 + F_EPS);
      const float upx = vpx * invp, upy = vpy * invp;
      const float a4 = upx * lx.x + upy * lx.y;
      const float a5 = upx * lxm1.x + upy * lxm1.y;
      float dotp2 = lx.x * lxm1.x + lx.y * lxm1.y;
      float cl2 = fminf(fmaxf(dotp2, -1.0f + F_EPS), 1.0f - F_EPS);
      const float f7o = (a4 < a5 ? 1.0f : -1.0f) * acosf(cl2);
      float du = ux * pux + uy * puy;
      float cl3 = fminf(fmaxf(du, -1.0f + F_EPS), 1.0f - F_EPS);
      const float d2 = acosf(cl3);

      const float rif[8] = {f4, d2, a1, a2, f3o, a4, a5, f7o};

      float h1v[32];
#pragma unroll
      for (int o = 0; o < 32; ++o) {
        float acc;
        if (P) {
          acc = b1p[o];
#pragma unroll
          for (int c = 0; c < 8; ++c) acc += w1p[o * 8 + c] * rif[c];
        } else {
          float a0 = 0.f;
#pragma unroll
          for (int c = 0; c < 8; ++c) a0 += ew1[o * 8 + c] * rif[c];
          const float sc = eg1[o] * rsqrtf(ev1[o] + F_BN_EPS);
          acc = (a0 + eb1[o] - em1[o]) * sc + ebeta1[o];
        }
        h1v[o] = fmaxf(acc, 0.f);
      }

#pragma unroll
      for (int i = 0; i < 8; ++i) {
        float yv[4];
#pragma unroll
        for (int j = 0; j < 4; ++j) {
          const int o = hf * 32 + i * 4 + j;
          float acc;
          if (P) {
            acc = b2p[o];
#pragma unroll
            for (int c = 0; c < 32; ++c) acc += w2p[o * 32 + c] * h1v[c];
          } else {
            float a0 = 0.f;
#pragma unroll
            for (int c = 0; c < 32; ++c) a0 += ew2[o * 32 + c] * h1v[c];
            const float sc = eg2[o] * rsqrtf(ev2[o] + F_BN_EPS);
            acc = (a0 + eb2[o] - em2[o]) * sc + ebeta2[o];
          }
          yv[j] = fmaxf(acc, 0.f);
        }
        const unsigned int u0 = (unsigned)f2bf(yv[0]) | ((unsigned)f2bf(yv[1]) << 16);
        const unsigned int u1 = (unsigned)f2bf(yv[2]) | ((unsigned)f2bf(yv[3]) << 16);
        *(uint2*)(smem + cat_off(m, 64 * hf + 8 * i)) = make_uint2(u0, u1);
      }
    }
    __syncthreads();

    {
      s16x8 B3[2][4];
      float bb3[2];
#pragma unroll
      for (int i = 0; i < 2; ++i) {
        const int o = (2 * w + i) * 16 + rl;
        if (P) {
#pragma unroll
          for (int kt = 0; kt < 4; ++kt)
            B3[i][kt] = *(const s16x8*)(wb3 + o * 128 + kt * 32 + 8 * g);
          bb3[i] = b3p[o];
        } else {
          const float sc = fg1[o] * rsqrtf(fv1[o] + F_BN_EPS);
#pragma unroll
          for (int kt = 0; kt < 4; ++kt)
            B3[i][kt] = pack_scaled(fw1 + o * 128 + kt * 32 + 8 * g, sc);
          bb3[i] = (fb1[o] - fm1[o]) * sc + fbeta1[o];
        }
      }
      for (int mt = 0; mt < 8; ++mt) {
        const int row = mt * 16 + rl;
        s16x8 a[4];
#pragma unroll
        for (int kt = 0; kt < 4; ++kt)
          a[kt] = __builtin_bit_cast(s16x8, *(const uint4*)(smem + cat_off(row, kt * 64 + 16 * g)));
#pragma unroll
        for (int i = 0; i < 2; ++i) {
          f32x4 acc = {0.f, 0.f, 0.f, 0.f};
          acc = __builtin_amdgcn_mfma_f32_16x16x32_bf16(a[0], B3[i][0], acc, 0, 0, 0);
          acc = __builtin_amdgcn_mfma_f32_16x16x32_bf16(a[1], B3[i][1], acc, 0, 0, 0);
          acc = __builtin_amdgcn_mfma_f32_16x16x32_bf16(a[2], B3[i][2], acc, 0, 0, 0);
          acc = __builtin_amdgcn_mfma_f32_16x16x32_bf16(a[3], B3[i][3], acc, 0, 0, 0);
          const int o = (2 * w + i) * 16 + rl;
#pragma unroll
          for (int r = 0; r < 4; ++r) {
            const float y = fmaxf(acc[r] + bb3[i], 0.f);
            *(unsigned short*)(smem + h3_off(mt * 16 + 4 * g + r, 2 * o)) = f2bf(y);
          }
        }
      }
    }
    __syncthreads();

#pragma unroll
    for (int nip = 0; nip < 2; ++nip) {
      s16x8 B4[2][4];
      float bb4[2];
#pragma unroll
      for (int q = 0; q < 2; ++q) {
        const int o = (4 * w + nip * 2 + q) * 16 + rl;
        if (P) {
#pragma unroll
          for (int kt = 0; kt < 4; ++kt)
            B4[q][kt] = *(const s16x8*)(wb4 + o * 128 + kt * 32 + 8 * g);
          bb4[q] = b4p[o];
        } else {
          const float sc = fg2[o] * rsqrtf(fv2[o] + F_BN_EPS);
#pragma unroll
          for (int kt = 0; kt < 4; ++kt)
            B4[q][kt] = pack_scaled(fw2 + o * 128 + kt * 32 + 8 * g, sc);
          bb4[q] = (fb2[o] - fm2[o]) * sc + fbeta2[o];
        }
      }
      float vm[2] = {-INFINITY, -INFINITY};
      for (int mt = 0; mt < 8; ++mt) {
        const int row = mt * 16 + rl;
        s16x8 a[4];
#pragma unroll
        for (int kt = 0; kt < 4; ++kt)
          a[kt] = __builtin_bit_cast(s16x8, *(const uint4*)(smem + h3_off(row, kt * 64 + 16 * g)));
#pragma unroll
        for (int q = 0; q < 2; ++q) {
          f32x4 acc = {0.f, 0.f, 0.f, 0.f};
          acc = __builtin_amdgcn_mfma_f32_16x16x32_bf16(a[0], B4[q][0], acc, 0, 0, 0);
          acc = __builtin_amdgcn_mfma_f32_16x16x32_bf16(a[1], B4[q][1], acc, 0, 0, 0);
          acc = __builtin_amdgcn_mfma_f32_16x16x32_bf16(a[2], B4[q][2], acc, 0, 0, 0);
          acc = __builtin_amdgcn_mfma_f32_16x16x32_bf16(a[3], B4[q][3], acc, 0, 0, 0);
#pragma unroll
          for (int r = 0; r < 4; ++r)
            vm[q] = fmaxf(vm[q], fmaxf(acc[r] + bb4[q], 0.f));
        }
        if (mt & 1) {
          const int sl = hh * 4 + (mt >> 1);
#pragma unroll
          for (int q = 0; q < 2; ++q) {
            float v = vm[q];
            v = fmaxf(v, __shfl_xor(v, 16));
            v = fmaxf(v, __shfl_xor(v, 32));
            if (g == 0) {
              const int o = (4 * w + nip * 2 + q) * 16 + rl;
              obuf[o * 9 + sl] = v;
            }
            vm[q] = -INFINITY;
          }
        }
      }
    }
  }

  __syncthreads();
  {
    float v[8];
#pragma unroll
    for (int j = 0; j < 8; ++j) v[j] = obuf[t * 9 + j];
    float* po = out + ((size_t)(b * 256 + t) << 10) + s_base;
    float4 v0; v0.x = v[0]; v0.y = v[1]; v0.z = v[2]; v0.w = v[3];
    float4 v1; v1.x = v[4]; v1.y = v[5]; v1.z = v[6]; v1.w = v[7];
    *(float4*)po = v0;
    *(float4*)(po + 4) = v1;
  }
}

}  // namespace

extern "C" void kernel_launch(void* const* d_in, const int* in_sizes, int n_in,
                              void* d_out, int out_size, void* d_ws, size_t ws_size,
                              hipStream_t stream) {
  (void)in_sizes; (void)n_in; (void)out_size;

  const float* contour = (const float*)d_in[0];
  const float* loa     = (const float*)d_in[1];
  const float* prev    = (const float*)d_in[2];
  const float* ew1 = (const float*)d_in[3];
  const float* eb1 = (const float*)d_in[4];
  const float* eg1 = (const float*)d_in[5];
  const float* ebeta1 = (const float*)d_in[6];
  const float* em1 = (const float*)d_in[7];
  const float* ev1 = (const float*)d_in[8];
  const float* ew2 = (const float*)d_in[9];
  const float* eb2 = (const float*)d_in[10];
  const float* eg2 = (const float*)d_in[11];
  const float* ebeta2 = (const float*)d_in[12];
  const float* em2 = (const float*)d_in[13];
  const float* ev2 = (const float*)d_in[14];
  const float* fw1 = (const float*)d_in[15];
  const float* fb1 = (const float*)d_in[16];
  const float* fg1 = (const float*)d_in[17];
  const float* fbeta1 = (const float*)d_in[18];
  const float* fm1 = (const float*)d_in[19];
  const float* fv1 = (const float*)d_in[20];
  const float* fw2 = (const float*)d_in[21];
  const float* fb2 = (const float*)d_in[22];
  const float* fg2 = (const float*)d_in[23];
  const float* fbeta2 = (const float*)d_in[24];
  const float* fm2 = (const float*)d_in[25];
  const float* fv2 = (const float*)d_in[26];

  float* out = (float*)d_out;
  unsigned char* ws = (unsigned char*)d_ws;

  if (ws && ws_size >= WS_BIG) {
    rcri_prep<<<dim3(331), dim3(256), 0, stream>>>(
        ew1, eb1, eg1, ebeta1, em1, ev1, ew2, eb2, eg2, ebeta2, em2, ev2,
        fw1, fb1, fg1, fbeta1, fm1, fv1, fw2, fb2, fg2, fbeta2, fm2, fv2, ws);
    rcri_tpose<<<dim3(512), dim3(256), 0, stream>>>(prev, ws);
    rcri_k1f2<<<dim3(2048), dim3(256), 0, stream>>>(contour, loa, ws);
    rcri_k23<<<dim3(2048), dim3(256), 0, stream>>>(ws, out);
  } else if (ws && ws_size >= WS_NEED) {
    rcri_prep<<<dim3(203), dim3(256), 0, stream>>>(
        ew1, eb1, eg1, ebeta1, em1, ev1, ew2, eb2, eg2, ebeta2, em2, ev2,
        fw1, fb1, fg1, fbeta1, fm1, fv1, fw2, fb2, fg2, fbeta2, fm2, fv2, ws);
    rcri_main<true><<<dim3(1024), dim3(256), 0, stream>>>(
        contour, loa, prev, ws,
        ew1, eb1, eg1, ebeta1, em1, ev1, ew2, eb2, eg2, ebeta2, em2, ev2,
        fw1, fb1, fg1, fbeta1, fm1, fv1, fw2, fb2, fg2, fbeta2, fm2, fv2, out);
  } else {
    rcri_main<false><<<dim3(1024), dim3(256), 0, stream>>>(
        contour, loa, prev, ws,
        ew1, eb1, eg1, ebeta1, em1, ev1, ew2, eb2, eg2, ebeta2, em2, ev2,
        fw1, fb1, fg1, fbeta1, fm1, fv1, fw2, fb2, fg2, fbeta2, fm2, fv2, out);
  }
}